// Round 2
// baseline (975.032 us; speedup 1.0000x reference)
//
#include <hip/hip_runtime.h>
#include <hip/hip_bf16.h>

#define N_FEAT 128
#define HIDDEN 64
#define N_CLS  40

// ---------------- edge layout detection / normalization ----------------
// If edge_index is int64 on device, the int32 view has high words == 0 at odd
// indices (values < 2^31). For int32 data, odd indices are random node ids.

__global__ void detect_layout_kernel(const int* __restrict__ ei, int* __restrict__ flag) {
    int lane = threadIdx.x;                 // 64 threads, one wave
    int v = ei[2 * lane + 1];
    unsigned long long b = __ballot(v != 0);
    if (lane == 0) flag[0] = (b == 0ull) ? 1 : 0;   // 1 => int64 layout
}

__global__ void normalize_edges_kernel(const int* __restrict__ ei, const int* __restrict__ flag,
                                       int* __restrict__ srcn, int* __restrict__ dstn, int E) {
    int e = blockIdx.x * blockDim.x + threadIdx.x;
    if (e >= E) return;
    if (flag[0]) {                          // int64: [src int64 x E][dst int64 x E]
        srcn[e] = ei[2 * e];
        dstn[e] = ei[2 * E + 2 * e];
    } else {                                // int32: [src x E][dst x E]
        srcn[e] = ei[e];
        dstn[e] = ei[E + e];
    }
}

// ---------------- degree / norm ----------------

__global__ void count_deg_kernel(const int* __restrict__ dst, unsigned* __restrict__ deg, int E) {
    int e = blockIdx.x * blockDim.x + threadIdx.x;
    if (e < E) atomicAdd(&deg[dst[e]], 1u);
}

__global__ void dinv_kernel(const unsigned* __restrict__ deg, float* __restrict__ dinv, int N) {
    int n = blockIdx.x * blockDim.x + threadIdx.x;
    if (n < N) dinv[n] = rsqrtf((float)(deg[n] + 1u));  // +1 self-loop => deg >= 1
}

// ---------------- GEMM1: x[N,128] @ W1[128,64] -> h[N,64] (f32) ----------------

__global__ __launch_bounds__(256) void gemm1_kernel(const float* __restrict__ x,
                                                    const float* __restrict__ W1,
                                                    float* __restrict__ h, int N) {
    __shared__ float Ws[N_FEAT * HIDDEN];   // 32 KB
    __shared__ float xs[4][N_FEAT];         // 2 KB
    int tid = threadIdx.x;
    for (int i = tid; i < N_FEAT * HIDDEN; i += 256)
        Ws[i] = W1[i];
    int row0 = blockIdx.x * 4;
    for (int i = tid; i < 4 * N_FEAT; i += 256) {
        int r = i >> 7, k = i & 127;
        int row = row0 + r;
        xs[r][k] = (row < N) ? x[(long long)row * N_FEAT + k] : 0.f;
    }
    __syncthreads();
    int r = tid >> 6;
    int j = tid & 63;
    int row = row0 + r;
    if (row >= N) return;
    float acc = 0.f;
#pragma unroll 8
    for (int k = 0; k < N_FEAT; ++k)
        acc += xs[r][k] * Ws[k * HIDDEN + j];
    h[(long long)row * HIDDEN + j] = acc;
}

// ---------------- GEMM2: act[N,64] @ W2[64,40] -> out[N,40] (f32) ----------------

__global__ __launch_bounds__(320) void gemm2_kernel(const float* __restrict__ act,
                                                    const float* __restrict__ W2,
                                                    float* __restrict__ out, int N) {
    __shared__ float Ws[HIDDEN * N_CLS];    // 10.2 KB
    __shared__ float xs[8][HIDDEN];         // 2 KB
    int tid = threadIdx.x;
    for (int i = tid; i < HIDDEN * N_CLS; i += 320)
        Ws[i] = W2[i];
    int row0 = blockIdx.x * 8;
    for (int i = tid; i < 8 * HIDDEN; i += 320) {
        int r = i >> 6, k = i & 63;
        int row = row0 + r;
        xs[r][k] = (row < N) ? act[(long long)row * HIDDEN + k] : 0.f;
    }
    __syncthreads();
    int r = tid / N_CLS;   // 0..7
    int j = tid % N_CLS;
    int row = row0 + r;
    if (row >= N) return;
    float acc = 0.f;
#pragma unroll 8
    for (int k = 0; k < HIDDEN; ++k)
        acc += xs[r][k] * Ws[k * N_CLS + j];
    out[(long long)row * N_CLS + j] = acc;
}

// ---------------- self-loop init: agg = h * dinv^2 ----------------

__global__ void init_self64_kernel(const float* __restrict__ h, const float* __restrict__ dinv,
                                   float* __restrict__ agg, int N) {
    int i = blockIdx.x * blockDim.x + threadIdx.x;
    if (i >= N * HIDDEN) return;
    int n = i >> 6;
    float dv = dinv[n];
    agg[i] = h[i] * dv * dv;
}

__global__ void init_self40_kernel(const float* __restrict__ h, const float* __restrict__ dinv,
                                   float* __restrict__ agg, int N) {
    int i = blockIdx.x * blockDim.x + threadIdx.x;
    if (i >= N * N_CLS) return;
    int n = i / N_CLS;
    float dv = dinv[n];
    agg[i] = h[i] * dv * dv;
}

// ---------------- edge scatter: agg[dst] += h[src] * dinv[src]*dinv[dst] ----------------

__global__ void scatter64_kernel(const float* __restrict__ h, float* __restrict__ agg,
                                 const int* __restrict__ src, const int* __restrict__ dst,
                                 const float* __restrict__ dinv, int E) {
    long long tid = (long long)blockIdx.x * blockDim.x + threadIdx.x;
    int e = (int)(tid >> 6);
    int f = (int)(tid & 63);
    if (e >= E) return;
    int s = src[e], d = dst[e];
    float norm = dinv[s] * dinv[d];
    atomicAdd(&agg[(long long)d * HIDDEN + f], h[(long long)s * HIDDEN + f] * norm);
}

__global__ void scatter40_kernel(const float* __restrict__ h, float* __restrict__ agg,
                                 const int* __restrict__ src, const int* __restrict__ dst,
                                 const float* __restrict__ dinv, int E) {
    long long tid = (long long)blockIdx.x * blockDim.x + threadIdx.x;
    if (tid >= (long long)E * N_CLS) return;
    int e = (int)(tid / N_CLS);
    int f = (int)(tid % N_CLS);
    int s = src[e], d = dst[e];
    float norm = dinv[s] * dinv[d];
    atomicAdd(&agg[(long long)d * N_CLS + f], h[(long long)s * N_CLS + f] * norm);
}

// ---------------- bias + relu (in place) ----------------

__global__ void relu_bias_kernel(float* __restrict__ agg, const float* __restrict__ b1, int total) {
    int i = blockIdx.x * blockDim.x + threadIdx.x;
    if (i >= total) return;
    float v = agg[i] + b1[i & 63];
    agg[i] = fmaxf(v, 0.f);
}

// ---------------- bias + log_softmax (one wave per row) ----------------

__global__ __launch_bounds__(256) void lsm_kernel(const float* __restrict__ agg,
                                                  const float* __restrict__ b2,
                                                  float* __restrict__ out, int N) {
    int wave = threadIdx.x >> 6;
    int lane = threadIdx.x & 63;
    int row = blockIdx.x * 4 + wave;
    if (row >= N) return;
    float val = 0.f;
    float v = -1e30f;
    if (lane < N_CLS) {
        val = agg[(long long)row * N_CLS + lane] + b2[lane];
        v = val;
    }
#pragma unroll
    for (int off = 32; off > 0; off >>= 1)
        v = fmaxf(v, __shfl_xor(v, off));
    float m = v;
    float ex = (lane < N_CLS) ? expf(val - m) : 0.f;
#pragma unroll
    for (int off = 32; off > 0; off >>= 1)
        ex += __shfl_xor(ex, off);
    float ls = logf(ex);
    if (lane < N_CLS)
        out[(long long)row * N_CLS + lane] = val - m - ls;
}

// ---------------- launch ----------------

static inline size_t align_up(size_t x) { return (x + 255) & ~(size_t)255; }

extern "C" void kernel_launch(void* const* d_in, const int* in_sizes, int n_in,
                              void* d_out, int out_size, void* d_ws, size_t ws_size,
                              hipStream_t stream) {
    const float* x  = (const float*)d_in[0];
    const int*   ei = (const int*)d_in[1];
    const float* W1 = (const float*)d_in[2];
    const float* b1 = (const float*)d_in[3];
    const float* W2 = (const float*)d_in[4];
    const float* b2 = (const float*)d_in[5];

    int N = in_sizes[0] / N_FEAT;     // 100000
    int E = in_sizes[1] / 2;          // 1600000

    // Workspace layout (~65 MB): flag | deg | dinv | srcn | dstn | buf1 | buf2
    char* ws = (char*)d_ws;
    int*      flag = (int*)ws;       ws += 256;
    unsigned* deg  = (unsigned*)ws;  ws += align_up((size_t)N * 4);
    float*    dinv = (float*)ws;     ws += align_up((size_t)N * 4);
    int*      srcn = (int*)ws;       ws += align_up((size_t)E * 4);
    int*      dstn = (int*)ws;       ws += align_up((size_t)E * 4);
    float*    buf1 = (float*)ws;     ws += align_up((size_t)N * HIDDEN * 4);  // h1, then h2
    float*    buf2 = (float*)ws;     ws += align_up((size_t)N * HIDDEN * 4);  // agg1/act, then agg2

    hipMemsetAsync(flag, 0, 256, stream);
    hipMemsetAsync(deg, 0, (size_t)N * 4, stream);

    detect_layout_kernel<<<1, 64, 0, stream>>>(ei, flag);
    normalize_edges_kernel<<<(E + 255) / 256, 256, 0, stream>>>(ei, flag, srcn, dstn, E);

    count_deg_kernel<<<(E + 255) / 256, 256, 0, stream>>>(dstn, deg, E);
    dinv_kernel<<<(N + 255) / 256, 256, 0, stream>>>(deg, dinv, N);

    // layer 1: h1 = x@W1 (buf1); agg1 (buf2) = scatter + self; act = relu(agg1 + b1) in place
    gemm1_kernel<<<(N + 3) / 4, 256, 0, stream>>>(x, W1, buf1, N);
    init_self64_kernel<<<(N * HIDDEN + 255) / 256, 256, 0, stream>>>(buf1, dinv, buf2, N);
    {
        long long total = (long long)E * HIDDEN;
        scatter64_kernel<<<(int)((total + 255) / 256), 256, 0, stream>>>(buf1, buf2, srcn, dstn, dinv, E);
    }
    relu_bias_kernel<<<(N * HIDDEN + 255) / 256, 256, 0, stream>>>(buf2, b1, N * HIDDEN);

    // layer 2: h2 = act@W2 (buf1, reused); agg2 (buf2, reused after gemm2 completes)
    gemm2_kernel<<<(N + 7) / 8, 320, 0, stream>>>(buf2, W2, buf1, N);
    init_self40_kernel<<<(N * N_CLS + 255) / 256, 256, 0, stream>>>(buf1, dinv, buf2, N);
    {
        long long total = (long long)E * N_CLS;
        scatter40_kernel<<<(int)((total + 255) / 256), 256, 0, stream>>>(buf1, buf2, srcn, dstn, dinv, E);
    }
    lsm_kernel<<<(N + 3) / 4, 256, 0, stream>>>(buf2, b2, (float*)d_out, N);
}

// Round 3
// 655.694 us; speedup vs baseline: 1.4870x; 1.4870x over previous
//
#include <hip/hip_runtime.h>
#include <hip/hip_bf16.h>

#define N_FEAT 128
#define HIDDEN 64
#define N_CLS  40
#define SCAN_B 256

// ---------------- edge layout detection ----------------
// int64 device layout => int32 view has zero high words at odd indices.

__global__ void detect_layout_kernel(const int* __restrict__ ei, int* __restrict__ flag) {
    int lane = threadIdx.x;                 // one wave
    int v = ei[2 * lane + 1];
    unsigned long long b = __ballot(v != 0);
    if (lane == 0) flag[0] = (b == 0ull) ? 1 : 0;   // 1 => int64 layout
}

// normalize edges to int32 src/dst arrays AND count in-degrees (fused)
__global__ void norm_count_kernel(const int* __restrict__ ei, const int* __restrict__ flag,
                                  int* __restrict__ srcn, int* __restrict__ dstn,
                                  unsigned* __restrict__ deg, int E) {
    int e = blockIdx.x * blockDim.x + threadIdx.x;
    if (e >= E) return;
    int s, d;
    if (flag[0]) {                          // int64: [src i64 x E][dst i64 x E]
        s = ei[2 * e];
        d = ei[2 * E + 2 * e];
    } else {                                // int32: [src x E][dst x E]
        s = ei[e];
        d = ei[E + e];
    }
    srcn[e] = s;
    dstn[e] = d;
    atomicAdd(&deg[d], 1u);
}

__global__ void dinv_kernel(const unsigned* __restrict__ deg, float* __restrict__ dinv, int N) {
    int n = blockIdx.x * blockDim.x + threadIdx.x;
    if (n < N) dinv[n] = rsqrtf((float)(deg[n] + 1u));  // +1 self-loop
}

// ---------------- exclusive scan of deg -> rowptr (3-kernel hierarchical) ----------------

__global__ void scan1_kernel(const unsigned* __restrict__ deg, unsigned* __restrict__ rowptr,
                             unsigned* __restrict__ blockSums, int N) {
    __shared__ unsigned tmp[SCAN_B];
    int i = blockIdx.x * SCAN_B + threadIdx.x;
    unsigned v = (i < N) ? deg[i] : 0u;
    tmp[threadIdx.x] = v;
    __syncthreads();
#pragma unroll
    for (int off = 1; off < SCAN_B; off <<= 1) {
        unsigned t = (threadIdx.x >= off) ? tmp[threadIdx.x - off] : 0u;
        __syncthreads();
        tmp[threadIdx.x] += t;
        __syncthreads();
    }
    if (i < N) rowptr[i] = tmp[threadIdx.x] - v;          // block-local exclusive
    if (threadIdx.x == SCAN_B - 1) blockSums[blockIdx.x] = tmp[threadIdx.x];
}

__global__ void scan2_kernel(unsigned* __restrict__ blockSums, int nb) {
    __shared__ unsigned tmp[512];
    unsigned v = (threadIdx.x < (unsigned)nb) ? blockSums[threadIdx.x] : 0u;
    tmp[threadIdx.x] = v;
    __syncthreads();
#pragma unroll
    for (int off = 1; off < 512; off <<= 1) {
        unsigned t = (threadIdx.x >= (unsigned)off) ? tmp[threadIdx.x - off] : 0u;
        __syncthreads();
        tmp[threadIdx.x] += t;
        __syncthreads();
    }
    if (threadIdx.x < (unsigned)nb) blockSums[threadIdx.x] = tmp[threadIdx.x] - v;  // exclusive
}

__global__ void scan3_kernel(unsigned* __restrict__ rowptr, const unsigned* __restrict__ blockSums, int N) {
    int i = blockIdx.x * SCAN_B + threadIdx.x;
    if (i < N) rowptr[i] += blockSums[blockIdx.x];
}

// ---------------- CSR fill (counting-sort placement) ----------------

__global__ void csr_fill_kernel(const int* __restrict__ src, const int* __restrict__ dst,
                                const unsigned* __restrict__ rowptr, unsigned* __restrict__ cursor,
                                int* __restrict__ csr_src, int E) {
    int e = blockIdx.x * blockDim.x + threadIdx.x;
    if (e >= E) return;
    int d = dst[e];
    unsigned slot = atomicAdd(&cursor[d], 1u);
    csr_src[rowptr[d] + slot] = src[e];
}

// ---------------- GEMM1: x[N,128] @ W1[128,64] -> h[N,64] (f32) ----------------

__global__ __launch_bounds__(256) void gemm1_kernel(const float* __restrict__ x,
                                                    const float* __restrict__ W1,
                                                    float* __restrict__ h, int N) {
    __shared__ float Ws[N_FEAT * HIDDEN];   // 32 KB
    __shared__ float xs[4][N_FEAT];         // 2 KB
    int tid = threadIdx.x;
    for (int i = tid; i < N_FEAT * HIDDEN; i += 256)
        Ws[i] = W1[i];
    int row0 = blockIdx.x * 4;
    for (int i = tid; i < 4 * N_FEAT; i += 256) {
        int r = i >> 7, k = i & 127;
        int row = row0 + r;
        xs[r][k] = (row < N) ? x[(long long)row * N_FEAT + k] : 0.f;
    }
    __syncthreads();
    int r = tid >> 6;
    int j = tid & 63;
    int row = row0 + r;
    if (row >= N) return;
    float acc = 0.f;
#pragma unroll 8
    for (int k = 0; k < N_FEAT; ++k)
        acc += xs[r][k] * Ws[k * HIDDEN + j];
    h[(long long)row * HIDDEN + j] = acc;
}

// ---------------- GEMM2: act[N,64] @ W2[64,40] -> h2[N,40] (f32) ----------------

__global__ __launch_bounds__(320) void gemm2_kernel(const float* __restrict__ act,
                                                    const float* __restrict__ W2,
                                                    float* __restrict__ out, int N) {
    __shared__ float Ws[HIDDEN * N_CLS];    // 10.2 KB
    __shared__ float xs[8][HIDDEN];         // 2 KB
    int tid = threadIdx.x;
    for (int i = tid; i < HIDDEN * N_CLS; i += 320)
        Ws[i] = W2[i];
    int row0 = blockIdx.x * 8;
    for (int i = tid; i < 8 * HIDDEN; i += 320) {
        int r = i >> 6, k = i & 63;
        int row = row0 + r;
        xs[r][k] = (row < N) ? act[(long long)row * HIDDEN + k] : 0.f;
    }
    __syncthreads();
    int r = tid / N_CLS;
    int j = tid % N_CLS;
    int row = row0 + r;
    if (row >= N) return;
    float acc = 0.f;
#pragma unroll 8
    for (int k = 0; k < HIDDEN; ++k)
        acc += xs[r][k] * Ws[k * N_CLS + j];
    out[(long long)row * N_CLS + j] = acc;
}

// ---------------- layer-1 aggregation: CSR gather + self-loop + bias + ReLU ----------------
// agg[d] = dinv[d] * ( sum_s dinv[s]*h[s] + dinv[d]*h[d] );  act = relu(agg + b1)

__global__ __launch_bounds__(256) void agg_relu64_kernel(const float* __restrict__ h,
                                                         const int* __restrict__ csr_src,
                                                         const unsigned* __restrict__ rowptr,
                                                         const unsigned* __restrict__ deg,
                                                         const float* __restrict__ dinv,
                                                         const float* __restrict__ b1,
                                                         float* __restrict__ act, int N) {
    int wave = threadIdx.x >> 6, lane = threadIdx.x & 63;
    int d = blockIdx.x * 4 + wave;
    if (d >= N) return;
    float dv = dinv[d];
    float acc = dv * h[(long long)d * HIDDEN + lane];
    unsigned beg = rowptr[d], len = deg[d];
#pragma unroll 4
    for (unsigned i = 0; i < len; ++i) {
        int s = csr_src[beg + i];
        acc += dinv[s] * h[(long long)s * HIDDEN + lane];
    }
    acc = acc * dv + b1[lane];
    act[(long long)d * HIDDEN + lane] = fmaxf(acc, 0.f);
}

// ---------------- layer-2 aggregation + bias + log_softmax (one wave per row) ----------------

__global__ __launch_bounds__(256) void agg_lsm40_kernel(const float* __restrict__ h2,
                                                        const int* __restrict__ csr_src,
                                                        const unsigned* __restrict__ rowptr,
                                                        const unsigned* __restrict__ deg,
                                                        const float* __restrict__ dinv,
                                                        const float* __restrict__ b2,
                                                        float* __restrict__ out, int N) {
    int wave = threadIdx.x >> 6, lane = threadIdx.x & 63;
    int d = blockIdx.x * 4 + wave;
    if (d >= N) return;
    float dv = dinv[d];
    float acc = 0.f;
    if (lane < N_CLS) acc = dv * h2[(long long)d * N_CLS + lane];
    unsigned beg = rowptr[d], len = deg[d];
#pragma unroll 4
    for (unsigned i = 0; i < len; ++i) {
        int s = csr_src[beg + i];
        float w = dinv[s];
        if (lane < N_CLS) acc += w * h2[(long long)s * N_CLS + lane];
    }
    float val = acc * dv + ((lane < N_CLS) ? b2[lane] : 0.f);
    float v = (lane < N_CLS) ? val : -1e30f;
#pragma unroll
    for (int off = 32; off > 0; off >>= 1)
        v = fmaxf(v, __shfl_xor(v, off));
    float ex = (lane < N_CLS) ? expf(val - v) : 0.f;
#pragma unroll
    for (int off = 32; off > 0; off >>= 1)
        ex += __shfl_xor(ex, off);
    float ls = logf(ex);
    if (lane < N_CLS)
        out[(long long)d * N_CLS + lane] = val - v - ls;
}

// ---------------- launch ----------------

static inline size_t align_up(size_t x) { return (x + 255) & ~(size_t)255; }

extern "C" void kernel_launch(void* const* d_in, const int* in_sizes, int n_in,
                              void* d_out, int out_size, void* d_ws, size_t ws_size,
                              hipStream_t stream) {
    const float* x  = (const float*)d_in[0];
    const int*   ei = (const int*)d_in[1];
    const float* W1 = (const float*)d_in[2];
    const float* b1 = (const float*)d_in[3];
    const float* W2 = (const float*)d_in[4];
    const float* b2 = (const float*)d_in[5];

    int N = in_sizes[0] / N_FEAT;     // 100000
    int E = in_sizes[1] / 2;          // 1600000
    int nb = (N + SCAN_B - 1) / SCAN_B;   // scan blocks (391)

    char* ws = (char*)d_ws;
    int*      flag    = (int*)ws;       ws += 256;
    unsigned* deg     = (unsigned*)ws;  ws += align_up((size_t)N * 4);
    float*    dinv    = (float*)ws;     ws += align_up((size_t)N * 4);
    unsigned* rowptr  = (unsigned*)ws;  ws += align_up((size_t)N * 4);
    unsigned* cursor  = (unsigned*)ws;  ws += align_up((size_t)N * 4);
    unsigned* bsums   = (unsigned*)ws;  ws += align_up((size_t)nb * 4);
    int*      srcn    = (int*)ws;       ws += align_up((size_t)E * 4);
    int*      dstn    = (int*)ws;       ws += align_up((size_t)E * 4);
    int*      csr_src = (int*)ws;       ws += align_up((size_t)E * 4);
    float*    buf1    = (float*)ws;     ws += align_up((size_t)N * HIDDEN * 4);  // h1, then h2
    float*    buf2    = (float*)ws;     ws += align_up((size_t)N * HIDDEN * 4);  // act

    hipMemsetAsync(deg, 0, (size_t)N * 4, stream);
    hipMemsetAsync(cursor, 0, (size_t)N * 4, stream);

    detect_layout_kernel<<<1, 64, 0, stream>>>(ei, flag);
    norm_count_kernel<<<(E + 255) / 256, 256, 0, stream>>>(ei, flag, srcn, dstn, deg, E);
    dinv_kernel<<<(N + 255) / 256, 256, 0, stream>>>(deg, dinv, N);

    scan1_kernel<<<nb, SCAN_B, 0, stream>>>(deg, rowptr, bsums, N);
    scan2_kernel<<<1, 512, 0, stream>>>(bsums, nb);
    scan3_kernel<<<nb, SCAN_B, 0, stream>>>(rowptr, bsums, N);
    csr_fill_kernel<<<(E + 255) / 256, 256, 0, stream>>>(srcn, dstn, rowptr, cursor, csr_src, E);

    // layer 1
    gemm1_kernel<<<(N + 3) / 4, 256, 0, stream>>>(x, W1, buf1, N);
    agg_relu64_kernel<<<(N + 3) / 4, 256, 0, stream>>>(buf1, csr_src, rowptr, deg, dinv, b1, buf2, N);

    // layer 2 (h2 reuses buf1; h1 dead after agg_relu64)
    gemm2_kernel<<<(N + 7) / 8, 320, 0, stream>>>(buf2, W2, buf1, N);
    agg_lsm40_kernel<<<(N + 3) / 4, 256, 0, stream>>>(buf1, csr_src, rowptr, deg, dinv, b2, (float*)d_out, N);
}

// Round 4
// 560.808 us; speedup vs baseline: 1.7386x; 1.1692x over previous
//
#include <hip/hip_runtime.h>
#include <hip/hip_bf16.h>
#include <string.h>

#define N_FEAT 128
#define HIDDEN 64
#define N_CLS  40
#define SCAN_B 256
#define G1_GROUPS 16
#define G2_GROUPS 8

// ---------------- bf16 pack/unpack (manual, RNE) ----------------

static __device__ inline unsigned pack_bf16(float a, float b) {
    unsigned ba = __float_as_uint(a);
    unsigned bb = __float_as_uint(b);
    unsigned ra = (ba + 0x7fffu + ((ba >> 16) & 1u)) >> 16;
    unsigned rb = (bb + 0x7fffu + ((bb >> 16) & 1u)) >> 16;
    return (ra & 0xffffu) | (rb << 16);
}

static __device__ inline float2 unpack_bf16(unsigned v) {
    return make_float2(__uint_as_float(v << 16), __uint_as_float(v & 0xffff0000u));
}

// ---------------- edge layout detection ----------------
// int64 device layout => int32 view has zero high words at odd indices.

__global__ void detect_layout_kernel(const int* __restrict__ ei, int* __restrict__ flag) {
    int lane = threadIdx.x;                 // one wave
    int v = ei[2 * lane + 1];
    unsigned long long b = __ballot(v != 0);
    if (lane == 0) flag[0] = (b == 0ull) ? 1 : 0;   // 1 => int64 layout
}

// count in-degrees straight from edge_index
__global__ void count_kernel(const int* __restrict__ ei, const int* __restrict__ flag,
                             unsigned* __restrict__ deg, int E) {
    int e = blockIdx.x * blockDim.x + threadIdx.x;
    if (e >= E) return;
    int d = flag[0] ? ei[2 * E + 2 * e] : ei[E + e];
    atomicAdd(&deg[d], 1u);
}

__global__ void dinv_kernel(const unsigned* __restrict__ deg, float* __restrict__ dinv, int N) {
    int n = blockIdx.x * blockDim.x + threadIdx.x;
    if (n < N) dinv[n] = rsqrtf((float)(deg[n] + 1u));  // +1 self-loop
}

// ---------------- exclusive scan of deg -> rowptr ----------------

__global__ void scan1_kernel(const unsigned* __restrict__ deg, unsigned* __restrict__ rowptr,
                             unsigned* __restrict__ blockSums, int N) {
    __shared__ unsigned tmp[SCAN_B];
    int i = blockIdx.x * SCAN_B + threadIdx.x;
    unsigned v = (i < N) ? deg[i] : 0u;
    tmp[threadIdx.x] = v;
    __syncthreads();
#pragma unroll
    for (int off = 1; off < SCAN_B; off <<= 1) {
        unsigned t = (threadIdx.x >= off) ? tmp[threadIdx.x - off] : 0u;
        __syncthreads();
        tmp[threadIdx.x] += t;
        __syncthreads();
    }
    if (i < N) rowptr[i] = tmp[threadIdx.x] - v;
    if (threadIdx.x == SCAN_B - 1) blockSums[blockIdx.x] = tmp[threadIdx.x];
}

__global__ void scan2_kernel(unsigned* __restrict__ blockSums, int nb) {
    __shared__ unsigned tmp[512];
    unsigned v = (threadIdx.x < (unsigned)nb) ? blockSums[threadIdx.x] : 0u;
    tmp[threadIdx.x] = v;
    __syncthreads();
#pragma unroll
    for (int off = 1; off < 512; off <<= 1) {
        unsigned t = (threadIdx.x >= (unsigned)off) ? tmp[threadIdx.x - off] : 0u;
        __syncthreads();
        tmp[threadIdx.x] += t;
        __syncthreads();
    }
    if (threadIdx.x < (unsigned)nb) blockSums[threadIdx.x] = tmp[threadIdx.x] - v;
}

__global__ void scan3_kernel(unsigned* __restrict__ rowptr, const unsigned* __restrict__ blockSums, int N) {
    int i = blockIdx.x * SCAN_B + threadIdx.x;
    if (i < N) rowptr[i] += blockSums[blockIdx.x];
}

// ---------------- CSR fill straight from edge_index ----------------

__global__ void csr_fill_kernel(const int* __restrict__ ei, const int* __restrict__ flag,
                                const unsigned* __restrict__ rowptr, unsigned* __restrict__ cursor,
                                int* __restrict__ csr_src, int E) {
    int e = blockIdx.x * blockDim.x + threadIdx.x;
    if (e >= E) return;
    int s, d;
    if (flag[0]) { s = ei[2 * e]; d = ei[2 * E + 2 * e]; }
    else         { s = ei[e];     d = ei[E + e]; }
    unsigned slot = atomicAdd(&cursor[d], 1u);
    csr_src[rowptr[d] + slot] = s;
}

// ---------------- GEMM1: x[N,128] @ W1[128,64] -> h1 bf16 [N,64] ----------------

__global__ __launch_bounds__(256) void gemm1_kernel(const float* __restrict__ x,
                                                    const float* __restrict__ W1,
                                                    unsigned* __restrict__ h1b, int N) {
    __shared__ float Ws[N_FEAT * HIDDEN];   // 32 KB
    __shared__ float xs[4][N_FEAT];         // 2 KB
    int tid = threadIdx.x;
    for (int i = tid; i < N_FEAT * HIDDEN; i += 256)
        Ws[i] = W1[i];
    int wave = tid >> 6, lane = tid & 63;
    for (int g = 0; g < G1_GROUPS; ++g) {
        int row0 = (blockIdx.x * G1_GROUPS + g) * 4;
        if (row0 >= N) break;
        __syncthreads();                    // protect xs reuse (also covers Ws on g=0 path below)
        for (int i = tid; i < 4 * N_FEAT; i += 256) {
            int r = i >> 7, k = i & 127;
            int row = row0 + r;
            xs[r][k] = (row < N) ? x[(size_t)row * N_FEAT + k] : 0.f;
        }
        __syncthreads();
        int row = row0 + wave;
        float acc = 0.f;
#pragma unroll 8
        for (int k = 0; k < N_FEAT; ++k)
            acc += xs[wave][k] * Ws[k * HIDDEN + lane];
        float nxt = __shfl_down(acc, 1);
        if (row < N && (lane & 1) == 0)
            h1b[(size_t)row * 32 + (lane >> 1)] = pack_bf16(acc, nxt);
    }
}

// ---------------- layer-1 agg: CSR gather (bf16) + self + bias + ReLU -> act bf16 ----------------
// act[d] = relu( dinv[d]*( sum_s dinv[s]*h[s] + dinv[d]*h[d] ) + b1 )

__global__ __launch_bounds__(256) void agg1_kernel(const unsigned* __restrict__ h1b,
                                                   const int* __restrict__ csr_src,
                                                   const unsigned* __restrict__ rowptr,
                                                   const unsigned* __restrict__ deg,
                                                   const float* __restrict__ dinv,
                                                   const float* __restrict__ b1,
                                                   unsigned* __restrict__ actb, int N) {
    int wave = threadIdx.x >> 6, lane = threadIdx.x & 63;
    int sub = lane >> 5, j = lane & 31;
    int d = blockIdx.x * 4 + wave;
    if (d >= N) return;
    float dv = dinv[d];
    float acc0 = 0.f, acc1 = 0.f;
    if (sub == 0) {
        float2 v = unpack_bf16(h1b[(size_t)d * 32 + j]);
        acc0 = dv * v.x; acc1 = dv * v.y;
    }
    unsigned beg = rowptr[d];
    int len = (int)deg[d];
    int i = 0;
    for (; i + 4 <= len; i += 4) {
        int sA = csr_src[beg + i + sub];
        int sB = csr_src[beg + i + 2 + sub];
        float wA = dinv[sA], wB = dinv[sB];
        unsigned vA = h1b[(size_t)sA * 32 + j];
        unsigned vB = h1b[(size_t)sB * 32 + j];
        float2 a = unpack_bf16(vA), b = unpack_bf16(vB);
        acc0 += wA * a.x + wB * b.x;
        acc1 += wA * a.y + wB * b.y;
    }
    for (; i < len; i += 2) {
        int e = i + sub;
        if (e < len) {
            int s = csr_src[beg + e];
            float w = dinv[s];
            float2 a = unpack_bf16(h1b[(size_t)s * 32 + j]);
            acc0 += w * a.x;
            acc1 += w * a.y;
        }
    }
    acc0 += __shfl_xor(acc0, 32);
    acc1 += __shfl_xor(acc1, 32);
    if (sub == 0) {
        float2 bb = ((const float2*)b1)[j];
        float r0 = fmaxf(acc0 * dv + bb.x, 0.f);
        float r1 = fmaxf(acc1 * dv + bb.y, 0.f);
        actb[(size_t)d * 32 + j] = pack_bf16(r0, r1);
    }
}

// ---------------- GEMM2: act bf16 [N,64] @ W2[64,40] -> h2 bf16 [N,40] ----------------

__global__ __launch_bounds__(320) void gemm2_kernel(const unsigned* __restrict__ actb,
                                                    const float* __restrict__ W2,
                                                    unsigned* __restrict__ h2b, int N) {
    __shared__ float Ws[HIDDEN * N_CLS];    // 10.2 KB
    __shared__ float xs[8][HIDDEN];         // 2 KB
    int tid = threadIdx.x;
    for (int i = tid; i < HIDDEN * N_CLS; i += 320)
        Ws[i] = W2[i];
    for (int g = 0; g < G2_GROUPS; ++g) {
        int row0 = (blockIdx.x * G2_GROUPS + g) * 8;
        if (row0 >= N) break;
        __syncthreads();
        for (int i = tid; i < 8 * 32; i += 320) {
            int r = i >> 5, k = i & 31;
            int row = row0 + r;
            float2 v = (row < N) ? unpack_bf16(actb[(size_t)row * 32 + k]) : make_float2(0.f, 0.f);
            xs[r][2 * k] = v.x;
            xs[r][2 * k + 1] = v.y;
        }
        __syncthreads();
        int r = tid / N_CLS, j = tid % N_CLS;
        int row = row0 + r;
        float acc = 0.f;
#pragma unroll 8
        for (int k = 0; k < HIDDEN; ++k)
            acc += xs[r][k] * Ws[k * N_CLS + j];
        float nxt = __shfl_down(acc, 1);    // j even => tid even => same wave
        if (row < N && (j & 1) == 0)
            h2b[(size_t)row * 20 + (j >> 1)] = pack_bf16(acc, nxt);
    }
}

// ---------------- layer-2 agg (bf16 gather) + bias + log_softmax -> out f32 ----------------

__global__ __launch_bounds__(256) void agg2_lsm_kernel(const unsigned* __restrict__ h2b,
                                                       const int* __restrict__ csr_src,
                                                       const unsigned* __restrict__ rowptr,
                                                       const unsigned* __restrict__ deg,
                                                       const float* __restrict__ dinv,
                                                       const float* __restrict__ b2,
                                                       float* __restrict__ out, int N) {
    int wave = threadIdx.x >> 6, lane = threadIdx.x & 63;
    int sub = lane >> 5, j = lane & 31;
    bool act = (j < 20);
    int d = blockIdx.x * 4 + wave;
    if (d >= N) return;
    float dv = dinv[d];
    float acc0 = 0.f, acc1 = 0.f;
    if (sub == 0 && act) {
        float2 v = unpack_bf16(h2b[(size_t)d * 20 + j]);
        acc0 = dv * v.x; acc1 = dv * v.y;
    }
    unsigned beg = rowptr[d];
    int len = (int)deg[d];
    int i = 0;
    for (; i + 4 <= len; i += 4) {
        int sA = csr_src[beg + i + sub];
        int sB = csr_src[beg + i + 2 + sub];
        float wA = dinv[sA], wB = dinv[sB];
        if (act) {
            float2 a = unpack_bf16(h2b[(size_t)sA * 20 + j]);
            float2 b = unpack_bf16(h2b[(size_t)sB * 20 + j]);
            acc0 += wA * a.x + wB * b.x;
            acc1 += wA * a.y + wB * b.y;
        }
    }
    for (; i < len; i += 2) {
        int e = i + sub;
        if (e < len && act) {
            int s = csr_src[beg + e];
            float w = dinv[s];
            float2 a = unpack_bf16(h2b[(size_t)s * 20 + j]);
            acc0 += w * a.x;
            acc1 += w * a.y;
        }
    }
    acc0 += __shfl_xor(acc0, 32);
    acc1 += __shfl_xor(acc1, 32);
    float v0 = -1e30f, v1 = -1e30f;
    if (act) {
        float2 bb = ((const float2*)b2)[j];
        v0 = acc0 * dv + bb.x;
        v1 = acc1 * dv + bb.y;
    }
    float m = fmaxf(v0, v1);
#pragma unroll
    for (int off = 32; off > 0; off >>= 1)
        m = fmaxf(m, __shfl_xor(m, off));
    float ex = (act && sub == 0) ? (expf(v0 - m) + expf(v1 - m)) : 0.f;  // count each class once
#pragma unroll
    for (int off = 32; off > 0; off >>= 1)
        ex += __shfl_xor(ex, off);
    float ls = logf(ex);
    if (act && sub == 0) {
        float2* orow = (float2*)(out + (size_t)d * N_CLS);
        orow[j] = make_float2(v0 - m - ls, v1 - m - ls);
    }
}

// ---------------- launch ----------------

static inline size_t align_up(size_t x) { return (x + 255) & ~(size_t)255; }

extern "C" void kernel_launch(void* const* d_in, const int* in_sizes, int n_in,
                              void* d_out, int out_size, void* d_ws, size_t ws_size,
                              hipStream_t stream) {
    const float* x  = (const float*)d_in[0];
    const int*   ei = (const int*)d_in[1];
    const float* W1 = (const float*)d_in[2];
    const float* b1 = (const float*)d_in[3];
    const float* W2 = (const float*)d_in[4];
    const float* b2 = (const float*)d_in[5];

    int N = in_sizes[0] / N_FEAT;     // 100000
    int E = in_sizes[1] / 2;          // 1600000
    int nb = (N + SCAN_B - 1) / SCAN_B;

    char* ws = (char*)d_ws;
    int*      flag    = (int*)ws;       ws += 256;
    unsigned* deg     = (unsigned*)ws;  ws += align_up((size_t)N * 4);
    float*    dinv    = (float*)ws;     ws += align_up((size_t)N * 4);
    unsigned* rowptr  = (unsigned*)ws;  ws += align_up((size_t)N * 4);
    unsigned* cursor  = (unsigned*)ws;  ws += align_up((size_t)N * 4);
    unsigned* bsums   = (unsigned*)ws;  ws += align_up((size_t)nb * 4);
    int*      csr_src = (int*)ws;       ws += align_up((size_t)E * 4);
    unsigned* h1b     = (unsigned*)ws;  ws += align_up((size_t)N * 32 * 4);   // bf16 [N,64]
    unsigned* actb    = (unsigned*)ws;  ws += align_up((size_t)N * 32 * 4);   // bf16 [N,64]
    unsigned* h2b     = (unsigned*)ws;  ws += align_up((size_t)N * 20 * 4);   // bf16 [N,40]

    hipMemsetAsync(deg, 0, (size_t)N * 4, stream);
    hipMemsetAsync(cursor, 0, (size_t)N * 4, stream);

    detect_layout_kernel<<<1, 64, 0, stream>>>(ei, flag);
    count_kernel<<<(E + 255) / 256, 256, 0, stream>>>(ei, flag, deg, E);
    dinv_kernel<<<(N + 255) / 256, 256, 0, stream>>>(deg, dinv, N);

    scan1_kernel<<<nb, SCAN_B, 0, stream>>>(deg, rowptr, bsums, N);
    scan2_kernel<<<1, 512, 0, stream>>>(bsums, nb);
    scan3_kernel<<<nb, SCAN_B, 0, stream>>>(rowptr, bsums, N);
    csr_fill_kernel<<<(E + 255) / 256, 256, 0, stream>>>(ei, flag, rowptr, cursor, csr_src, E);

    // layer 1
    int g1_blocks = (N + 4 * G1_GROUPS - 1) / (4 * G1_GROUPS);
    gemm1_kernel<<<g1_blocks, 256, 0, stream>>>(x, W1, h1b, N);
    agg1_kernel<<<(N + 3) / 4, 256, 0, stream>>>(h1b, csr_src, rowptr, deg, dinv, b1, actb, N);

    // layer 2
    int g2_blocks = (N + 8 * G2_GROUPS - 1) / (8 * G2_GROUPS);
    gemm2_kernel<<<g2_blocks, 320, 0, stream>>>(actb, W2, h2b, N);
    agg2_lsm_kernel<<<(N + 3) / 4, 256, 0, stream>>>(h2b, csr_src, rowptr, deg, dinv, b2, (float*)d_out, N);
}

// Round 5
// 522.067 us; speedup vs baseline: 1.8676x; 1.0742x over previous
//
#include <hip/hip_runtime.h>
#include <hip/hip_bf16.h>
#include <string.h>

#define N_FEAT 128
#define HIDDEN 64
#define N_CLS  40
#define SCAN_B 256
#define G1_GROUPS 16
#define G2_GROUPS 8
#define FILL_BLOCKS 1024   // 8 range-groups x 128 blocks

// ---------------- bf16 pack/unpack (manual, RNE) ----------------

static __device__ inline unsigned pack_bf16(float a, float b) {
    unsigned ba = __float_as_uint(a);
    unsigned bb = __float_as_uint(b);
    unsigned ra = (ba + 0x7fffu + ((ba >> 16) & 1u)) >> 16;
    unsigned rb = (bb + 0x7fffu + ((bb >> 16) & 1u)) >> 16;
    return (ra & 0xffffu) | (rb << 16);
}

static __device__ inline float2 unpack_bf16(unsigned v) {
    return make_float2(__uint_as_float(v << 16), __uint_as_float(v & 0xffff0000u));
}

// ---------------- edge layout detection ----------------
// int64 device layout => int32 view has zero high words at odd indices.

__global__ void detect_layout_kernel(const int* __restrict__ ei, int* __restrict__ flag) {
    int lane = threadIdx.x;                 // one wave
    int v = ei[2 * lane + 1];
    unsigned long long b = __ballot(v != 0);
    if (lane == 0) flag[0] = (b == 0ull) ? 1 : 0;   // 1 => int64 layout
}

// ---------------- degree count, XCD-range partitioned ----------------
// blockIdx%8 selects a dst range; that group's blocks scan ALL edges and count
// only in-range dsts, so each deg slice stays in one XCD's L2.

__global__ __launch_bounds__(256) void count_kernel(const int* __restrict__ ei,
                                                    const int* __restrict__ flag,
                                                    unsigned* __restrict__ deg, int E, int N) {
    int r  = blockIdx.x & 7;
    int gb = blockIdx.x >> 3;
    int nb = gridDim.x >> 3;
    int rng = (N + 7) >> 3;
    int lo = r * rng;
    int hi = min(N, lo + rng);
    bool is64 = (flag[0] != 0);
    const int* dstp = is64 ? (ei + 2 * E) : (ei + E);
    int stride = is64 ? 2 : 1;
    for (int e = gb * 256 + threadIdx.x; e < E; e += nb * 256) {
        int d = dstp[(size_t)e * stride];
        if (d >= lo && d < hi) atomicAdd(&deg[d], 1u);
    }
}

__global__ void dinv_kernel(const unsigned* __restrict__ deg, float* __restrict__ dinv, int N) {
    int n = blockIdx.x * blockDim.x + threadIdx.x;
    if (n < N) dinv[n] = rsqrtf((float)(deg[n] + 1u));  // +1 self-loop
}

// ---------------- exclusive scan of deg -> rowptr ----------------

__global__ void scan1_kernel(const unsigned* __restrict__ deg, unsigned* __restrict__ rowptr,
                             unsigned* __restrict__ blockSums, int N) {
    __shared__ unsigned tmp[SCAN_B];
    int i = blockIdx.x * SCAN_B + threadIdx.x;
    unsigned v = (i < N) ? deg[i] : 0u;
    tmp[threadIdx.x] = v;
    __syncthreads();
#pragma unroll
    for (int off = 1; off < SCAN_B; off <<= 1) {
        unsigned t = (threadIdx.x >= off) ? tmp[threadIdx.x - off] : 0u;
        __syncthreads();
        tmp[threadIdx.x] += t;
        __syncthreads();
    }
    if (i < N) rowptr[i] = tmp[threadIdx.x] - v;
    if (threadIdx.x == SCAN_B - 1) blockSums[blockIdx.x] = tmp[threadIdx.x];
}

__global__ void scan2_kernel(unsigned* __restrict__ blockSums, int nb) {
    __shared__ unsigned tmp[512];
    unsigned v = (threadIdx.x < (unsigned)nb) ? blockSums[threadIdx.x] : 0u;
    tmp[threadIdx.x] = v;
    __syncthreads();
#pragma unroll
    for (int off = 1; off < 512; off <<= 1) {
        unsigned t = (threadIdx.x >= (unsigned)off) ? tmp[threadIdx.x - off] : 0u;
        __syncthreads();
        tmp[threadIdx.x] += t;
        __syncthreads();
    }
    if (threadIdx.x < (unsigned)nb) blockSums[threadIdx.x] = tmp[threadIdx.x] - v;
}

// writes rowptr += base AND initializes cursor = rowptr (absolute slot cursors)
__global__ void scan3_kernel(unsigned* __restrict__ rowptr, const unsigned* __restrict__ blockSums,
                             unsigned* __restrict__ cursor, int N) {
    int i = blockIdx.x * SCAN_B + threadIdx.x;
    if (i < N) {
        unsigned v = rowptr[i] + blockSums[blockIdx.x];
        rowptr[i] = v;
        cursor[i] = v;
    }
}

// ---------------- CSR fill, XCD-range partitioned ----------------
// Same grouping as count_kernel: all writes to a given csr_src slice come from
// one XCD, so 64B lines are fully assembled in its L2 before writeback.

__global__ __launch_bounds__(256) void csr_fill_kernel(const int* __restrict__ ei,
                                                       const int* __restrict__ flag,
                                                       unsigned* __restrict__ cursor,
                                                       int* __restrict__ csr_src, int E, int N) {
    int r  = blockIdx.x & 7;
    int gb = blockIdx.x >> 3;
    int nb = gridDim.x >> 3;
    int rng = (N + 7) >> 3;
    int lo = r * rng;
    int hi = min(N, lo + rng);
    bool is64 = (flag[0] != 0);
    const int* srcp = is64 ? ei : ei;
    const int* dstp = is64 ? (ei + 2 * E) : (ei + E);
    int stride = is64 ? 2 : 1;
    for (int e = gb * 256 + threadIdx.x; e < E; e += nb * 256) {
        int d = dstp[(size_t)e * stride];
        if (d >= lo && d < hi) {
            int s = srcp[(size_t)e * stride];
            unsigned slot = atomicAdd(&cursor[d], 1u);
            csr_src[slot] = s;
        }
    }
}

// ---------------- GEMM1: x[N,128] @ W1[128,64] -> h1 bf16 [N,64] ----------------

__global__ __launch_bounds__(256) void gemm1_kernel(const float* __restrict__ x,
                                                    const float* __restrict__ W1,
                                                    unsigned* __restrict__ h1b, int N) {
    __shared__ float Ws[N_FEAT * HIDDEN];   // 32 KB
    __shared__ float xs[4][N_FEAT];         // 2 KB
    int tid = threadIdx.x;
    for (int i = tid; i < N_FEAT * HIDDEN; i += 256)
        Ws[i] = W1[i];
    int wave = tid >> 6, lane = tid & 63;
    for (int g = 0; g < G1_GROUPS; ++g) {
        int row0 = (blockIdx.x * G1_GROUPS + g) * 4;
        if (row0 >= N) break;
        __syncthreads();
        for (int i = tid; i < 4 * N_FEAT; i += 256) {
            int r = i >> 7, k = i & 127;
            int row = row0 + r;
            xs[r][k] = (row < N) ? x[(size_t)row * N_FEAT + k] : 0.f;
        }
        __syncthreads();
        int row = row0 + wave;
        float acc = 0.f;
#pragma unroll 8
        for (int k = 0; k < N_FEAT; ++k)
            acc += xs[wave][k] * Ws[k * HIDDEN + lane];
        float nxt = __shfl_down(acc, 1);
        if (row < N && (lane & 1) == 0)
            h1b[(size_t)row * 32 + (lane >> 1)] = pack_bf16(acc, nxt);
    }
}

// ---------------- layer-1 agg: CSR gather (bf16) + self + bias + ReLU -> act bf16 ----------------

__global__ __launch_bounds__(256) void agg1_kernel(const unsigned* __restrict__ h1b,
                                                   const int* __restrict__ csr_src,
                                                   const unsigned* __restrict__ rowptr,
                                                   const unsigned* __restrict__ deg,
                                                   const float* __restrict__ dinv,
                                                   const float* __restrict__ b1,
                                                   unsigned* __restrict__ actb, int N) {
    int wave = threadIdx.x >> 6, lane = threadIdx.x & 63;
    int sub = lane >> 5, j = lane & 31;
    int d = blockIdx.x * 4 + wave;
    if (d >= N) return;
    float dv = dinv[d];
    float acc0 = 0.f, acc1 = 0.f;
    if (sub == 0) {
        float2 v = unpack_bf16(h1b[(size_t)d * 32 + j]);
        acc0 = dv * v.x; acc1 = dv * v.y;
    }
    unsigned beg = rowptr[d];
    int len = (int)deg[d];
    int i = 0;
    for (; i + 4 <= len; i += 4) {
        int sA = csr_src[beg + i + sub];
        int sB = csr_src[beg + i + 2 + sub];
        float wA = dinv[sA], wB = dinv[sB];
        unsigned vA = h1b[(size_t)sA * 32 + j];
        unsigned vB = h1b[(size_t)sB * 32 + j];
        float2 a = unpack_bf16(vA), b = unpack_bf16(vB);
        acc0 += wA * a.x + wB * b.x;
        acc1 += wA * a.y + wB * b.y;
    }
    for (; i < len; i += 2) {
        int e = i + sub;
        if (e < len) {
            int s = csr_src[beg + e];
            float w = dinv[s];
            float2 a = unpack_bf16(h1b[(size_t)s * 32 + j]);
            acc0 += w * a.x;
            acc1 += w * a.y;
        }
    }
    acc0 += __shfl_xor(acc0, 32);
    acc1 += __shfl_xor(acc1, 32);
    if (sub == 0) {
        float2 bb = ((const float2*)b1)[j];
        float r0 = fmaxf(acc0 * dv + bb.x, 0.f);
        float r1 = fmaxf(acc1 * dv + bb.y, 0.f);
        actb[(size_t)d * 32 + j] = pack_bf16(r0, r1);
    }
}

// ---------------- GEMM2: act bf16 [N,64] @ W2[64,40] -> h2 bf16 [N,40] ----------------

__global__ __launch_bounds__(320) void gemm2_kernel(const unsigned* __restrict__ actb,
                                                    const float* __restrict__ W2,
                                                    unsigned* __restrict__ h2b, int N) {
    __shared__ float Ws[HIDDEN * N_CLS];    // 10.2 KB
    __shared__ float xs[8][HIDDEN];         // 2 KB
    int tid = threadIdx.x;
    for (int i = tid; i < HIDDEN * N_CLS; i += 320)
        Ws[i] = W2[i];
    for (int g = 0; g < G2_GROUPS; ++g) {
        int row0 = (blockIdx.x * G2_GROUPS + g) * 8;
        if (row0 >= N) break;
        __syncthreads();
        for (int i = tid; i < 8 * 32; i += 320) {
            int r = i >> 5, k = i & 31;
            int row = row0 + r;
            float2 v = (row < N) ? unpack_bf16(actb[(size_t)row * 32 + k]) : make_float2(0.f, 0.f);
            xs[r][2 * k] = v.x;
            xs[r][2 * k + 1] = v.y;
        }
        __syncthreads();
        int r = tid / N_CLS, j = tid % N_CLS;
        int row = row0 + r;
        float acc = 0.f;
#pragma unroll 8
        for (int k = 0; k < HIDDEN; ++k)
            acc += xs[r][k] * Ws[k * N_CLS + j];
        float nxt = __shfl_down(acc, 1);
        if (row < N && (j & 1) == 0)
            h2b[(size_t)row * 20 + (j >> 1)] = pack_bf16(acc, nxt);
    }
}

// ---------------- layer-2 agg (bf16 gather) + bias + log_softmax -> out f32 ----------------

__global__ __launch_bounds__(256) void agg2_lsm_kernel(const unsigned* __restrict__ h2b,
                                                       const int* __restrict__ csr_src,
                                                       const unsigned* __restrict__ rowptr,
                                                       const unsigned* __restrict__ deg,
                                                       const float* __restrict__ dinv,
                                                       const float* __restrict__ b2,
                                                       float* __restrict__ out, int N) {
    int wave = threadIdx.x >> 6, lane = threadIdx.x & 63;
    int sub = lane >> 5, j = lane & 31;
    bool act = (j < 20);
    int d = blockIdx.x * 4 + wave;
    if (d >= N) return;
    float dv = dinv[d];
    float acc0 = 0.f, acc1 = 0.f;
    if (sub == 0 && act) {
        float2 v = unpack_bf16(h2b[(size_t)d * 20 + j]);
        acc0 = dv * v.x; acc1 = dv * v.y;
    }
    unsigned beg = rowptr[d];
    int len = (int)deg[d];
    int i = 0;
    for (; i + 4 <= len; i += 4) {
        int sA = csr_src[beg + i + sub];
        int sB = csr_src[beg + i + 2 + sub];
        float wA = dinv[sA], wB = dinv[sB];
        if (act) {
            float2 a = unpack_bf16(h2b[(size_t)sA * 20 + j]);
            float2 b = unpack_bf16(h2b[(size_t)sB * 20 + j]);
            acc0 += wA * a.x + wB * b.x;
            acc1 += wA * a.y + wB * b.y;
        }
    }
    for (; i < len; i += 2) {
        int e = i + sub;
        if (e < len && act) {
            int s = csr_src[beg + e];
            float w = dinv[s];
            float2 a = unpack_bf16(h2b[(size_t)s * 20 + j]);
            acc0 += w * a.x;
            acc1 += w * a.y;
        }
    }
    acc0 += __shfl_xor(acc0, 32);
    acc1 += __shfl_xor(acc1, 32);
    float v0 = -1e30f, v1 = -1e30f;
    if (act) {
        float2 bb = ((const float2*)b2)[j];
        v0 = acc0 * dv + bb.x;
        v1 = acc1 * dv + bb.y;
    }
    float m = fmaxf(v0, v1);
#pragma unroll
    for (int off = 32; off > 0; off >>= 1)
        m = fmaxf(m, __shfl_xor(m, off));
    float ex = (act && sub == 0) ? (expf(v0 - m) + expf(v1 - m)) : 0.f;
#pragma unroll
    for (int off = 32; off > 0; off >>= 1)
        ex += __shfl_xor(ex, off);
    float ls = logf(ex);
    if (act && sub == 0) {
        float2* orow = (float2*)(out + (size_t)d * N_CLS);
        orow[j] = make_float2(v0 - m - ls, v1 - m - ls);
    }
}

// ---------------- launch ----------------

static inline size_t align_up(size_t x) { return (x + 255) & ~(size_t)255; }

extern "C" void kernel_launch(void* const* d_in, const int* in_sizes, int n_in,
                              void* d_out, int out_size, void* d_ws, size_t ws_size,
                              hipStream_t stream) {
    const float* x  = (const float*)d_in[0];
    const int*   ei = (const int*)d_in[1];
    const float* W1 = (const float*)d_in[2];
    const float* b1 = (const float*)d_in[3];
    const float* W2 = (const float*)d_in[4];
    const float* b2 = (const float*)d_in[5];

    int N = in_sizes[0] / N_FEAT;     // 100000
    int E = in_sizes[1] / 2;          // 1600000
    int nb = (N + SCAN_B - 1) / SCAN_B;

    char* ws = (char*)d_ws;
    int*      flag    = (int*)ws;       ws += 256;
    unsigned* deg     = (unsigned*)ws;  ws += align_up((size_t)N * 4);
    float*    dinv    = (float*)ws;     ws += align_up((size_t)N * 4);
    unsigned* rowptr  = (unsigned*)ws;  ws += align_up((size_t)N * 4);
    unsigned* cursor  = (unsigned*)ws;  ws += align_up((size_t)N * 4);
    unsigned* bsums   = (unsigned*)ws;  ws += align_up((size_t)nb * 4);
    int*      csr_src = (int*)ws;       ws += align_up((size_t)E * 4);
    unsigned* h1b     = (unsigned*)ws;  ws += align_up((size_t)N * 32 * 4);   // bf16 [N,64]
    unsigned* actb    = (unsigned*)ws;  ws += align_up((size_t)N * 32 * 4);   // bf16 [N,64]
    unsigned* h2b     = (unsigned*)ws;  ws += align_up((size_t)N * 20 * 4);   // bf16 [N,40]

    hipMemsetAsync(deg, 0, (size_t)N * 4, stream);

    detect_layout_kernel<<<1, 64, 0, stream>>>(ei, flag);
    count_kernel<<<FILL_BLOCKS, 256, 0, stream>>>(ei, flag, deg, E, N);
    dinv_kernel<<<(N + 255) / 256, 256, 0, stream>>>(deg, dinv, N);

    scan1_kernel<<<nb, SCAN_B, 0, stream>>>(deg, rowptr, bsums, N);
    scan2_kernel<<<1, 512, 0, stream>>>(bsums, nb);
    scan3_kernel<<<nb, SCAN_B, 0, stream>>>(rowptr, bsums, cursor, N);
    csr_fill_kernel<<<FILL_BLOCKS, 256, 0, stream>>>(ei, flag, cursor, csr_src, E, N);

    // layer 1
    int g1_blocks = (N + 4 * G1_GROUPS - 1) / (4 * G1_GROUPS);
    gemm1_kernel<<<g1_blocks, 256, 0, stream>>>(x, W1, h1b, N);
    agg1_kernel<<<(N + 3) / 4, 256, 0, stream>>>(h1b, csr_src, rowptr, deg, dinv, b1, actb, N);

    // layer 2
    int g2_blocks = (N + 8 * G2_GROUPS - 1) / (8 * G2_GROUPS);
    gemm2_kernel<<<g2_blocks, 320, 0, stream>>>(actb, W2, h2b, N);
    agg2_lsm_kernel<<<(N + 3) / 4, 256, 0, stream>>>(h2b, csr_src, rowptr, deg, dinv, b2, (float*)d_out, N);
}

// Round 6
// 401.891 us; speedup vs baseline: 2.4261x; 1.2990x over previous
//
#include <hip/hip_runtime.h>
#include <hip/hip_bf16.h>
#include <string.h>

#define N_FEAT 128
#define HIDDEN 64
#define N_CLS  40
#define SCAN_B 256
#define FILL_BLOCKS 1024   // 8 range-groups x 128 blocks

typedef __bf16 bf16x8 __attribute__((ext_vector_type(8)));
typedef float  f32x4  __attribute__((ext_vector_type(4)));

union Frag { unsigned u[4]; bf16x8 v; };

// ---------------- bf16 pack/unpack (manual, RNE) ----------------

static __device__ inline unsigned pack_bf16(float a, float b) {
    unsigned ba = __float_as_uint(a);
    unsigned bb = __float_as_uint(b);
    unsigned ra = (ba + 0x7fffu + ((ba >> 16) & 1u)) >> 16;
    unsigned rb = (bb + 0x7fffu + ((bb >> 16) & 1u)) >> 16;
    return (ra & 0xffffu) | (rb << 16);
}

static __device__ inline float2 unpack_bf16(unsigned v) {
    return make_float2(__uint_as_float(v << 16), __uint_as_float(v & 0xffff0000u));
}

// ---------------- edge layout detection ----------------

__global__ void detect_layout_kernel(const int* __restrict__ ei, int* __restrict__ flag) {
    int lane = threadIdx.x;                 // one wave
    int v = ei[2 * lane + 1];
    unsigned long long b = __ballot(v != 0);
    if (lane == 0) flag[0] = (b == 0ull) ? 1 : 0;   // 1 => int64 layout
}

// ---------------- degree count, XCD-range partitioned ----------------

__global__ __launch_bounds__(256) void count_kernel(const int* __restrict__ ei,
                                                    const int* __restrict__ flag,
                                                    unsigned* __restrict__ deg, int E, int N) {
    int r  = blockIdx.x & 7;
    int gb = blockIdx.x >> 3;
    int nb = gridDim.x >> 3;
    int rng = (N + 7) >> 3;
    int lo = r * rng;
    int hi = min(N, lo + rng);
    bool is64 = (flag[0] != 0);
    const int* dstp = is64 ? (ei + 2 * E) : (ei + E);
    int stride = is64 ? 2 : 1;
    for (int e = gb * 256 + threadIdx.x; e < E; e += nb * 256) {
        int d = dstp[(size_t)e * stride];
        if (d >= lo && d < hi) atomicAdd(&deg[d], 1u);
    }
}

__global__ void dinv_kernel(const unsigned* __restrict__ deg, float* __restrict__ dinv, int N) {
    int n = blockIdx.x * blockDim.x + threadIdx.x;
    if (n < N) dinv[n] = rsqrtf((float)(deg[n] + 1u));  // +1 self-loop
}

// ---------------- exclusive scan of deg -> rowptr ----------------

__global__ void scan1_kernel(const unsigned* __restrict__ deg, unsigned* __restrict__ rowptr,
                             unsigned* __restrict__ blockSums, int N) {
    __shared__ unsigned tmp[SCAN_B];
    int i = blockIdx.x * SCAN_B + threadIdx.x;
    unsigned v = (i < N) ? deg[i] : 0u;
    tmp[threadIdx.x] = v;
    __syncthreads();
#pragma unroll
    for (int off = 1; off < SCAN_B; off <<= 1) {
        unsigned t = (threadIdx.x >= off) ? tmp[threadIdx.x - off] : 0u;
        __syncthreads();
        tmp[threadIdx.x] += t;
        __syncthreads();
    }
    if (i < N) rowptr[i] = tmp[threadIdx.x] - v;
    if (threadIdx.x == SCAN_B - 1) blockSums[blockIdx.x] = tmp[threadIdx.x];
}

__global__ void scan2_kernel(unsigned* __restrict__ blockSums, int nb) {
    __shared__ unsigned tmp[512];
    unsigned v = (threadIdx.x < (unsigned)nb) ? blockSums[threadIdx.x] : 0u;
    tmp[threadIdx.x] = v;
    __syncthreads();
#pragma unroll
    for (int off = 1; off < 512; off <<= 1) {
        unsigned t = (threadIdx.x >= (unsigned)off) ? tmp[threadIdx.x - off] : 0u;
        __syncthreads();
        tmp[threadIdx.x] += t;
        __syncthreads();
    }
    if (threadIdx.x < (unsigned)nb) blockSums[threadIdx.x] = tmp[threadIdx.x] - v;
}

__global__ void scan3_kernel(unsigned* __restrict__ rowptr, const unsigned* __restrict__ blockSums,
                             unsigned* __restrict__ cursor, int N) {
    int i = blockIdx.x * SCAN_B + threadIdx.x;
    if (i < N) {
        unsigned v = rowptr[i] + blockSums[blockIdx.x];
        rowptr[i] = v;
        cursor[i] = v;
    }
}

// ---------------- CSR fill, XCD-range partitioned ----------------

__global__ __launch_bounds__(256) void csr_fill_kernel(const int* __restrict__ ei,
                                                       const int* __restrict__ flag,
                                                       unsigned* __restrict__ cursor,
                                                       int* __restrict__ csr_src, int E, int N) {
    int r  = blockIdx.x & 7;
    int gb = blockIdx.x >> 3;
    int nb = gridDim.x >> 3;
    int rng = (N + 7) >> 3;
    int lo = r * rng;
    int hi = min(N, lo + rng);
    bool is64 = (flag[0] != 0);
    const int* dstp = is64 ? (ei + 2 * E) : (ei + E);
    int stride = is64 ? 2 : 1;
    for (int e = gb * 256 + threadIdx.x; e < E; e += nb * 256) {
        int d = dstp[(size_t)e * stride];
        if (d >= lo && d < hi) {
            int s = ei[(size_t)e * stride];
            unsigned slot = atomicAdd(&cursor[d], 1u);
            csr_src[slot] = s;
        }
    }
}

// ---------------- GEMM1 (MFMA): x[N,128] f32 @ W1[128,64] f32 -> h1 bf16 [N,64] ----------------
// One wave per 16-row tile. A: global float4 loads + bf16 pack. B: register-resident W1 frags.
// mfma_f32_16x16x32_bf16 layouts: A[m=lane&15][k=quad*8+j]; B[k=quad*8+j][n=lane&15];
// D: col=lane&15, row=quad*4+reg.

__global__ __launch_bounds__(256) void gemm1_mfma_kernel(const float* __restrict__ x,
                                                         const float* __restrict__ W1,
                                                         unsigned* __restrict__ h1b, int N) {
    int lane = threadIdx.x & 63;
    int quad = lane >> 4;
    int col  = lane & 15;

    // B-frags: 4 col-tiles x 4 k-steps
    Frag B[4][4];
#pragma unroll
    for (int c = 0; c < 4; ++c)
#pragma unroll
        for (int ks = 0; ks < 4; ++ks) {
            int n = c * 16 + col;
#pragma unroll
            for (int jj = 0; jj < 4; ++jj) {
                int k = ks * 32 + quad * 8 + 2 * jj;
                B[c][ks].u[jj] = pack_bf16(W1[k * HIDDEN + n], W1[(k + 1) * HIDDEN + n]);
            }
        }

    int wave_id = blockIdx.x * 4 + (threadIdx.x >> 6);
    int nwaves  = gridDim.x * 4;
    int ntiles  = (N + 15) >> 4;

    for (int rt = wave_id; rt < ntiles; rt += nwaves) {
        int rowA = rt * 16 + col;               // A-fragment row for this lane
        Frag A[4];
#pragma unroll
        for (int ks = 0; ks < 4; ++ks) {
            float4 a0 = make_float4(0.f, 0.f, 0.f, 0.f), a1 = a0;
            if (rowA < N) {
                const float4* ap = (const float4*)(x + (size_t)rowA * N_FEAT + ks * 32 + quad * 8);
                a0 = ap[0];
                a1 = ap[1];
            }
            A[ks].u[0] = pack_bf16(a0.x, a0.y);
            A[ks].u[1] = pack_bf16(a0.z, a0.w);
            A[ks].u[2] = pack_bf16(a1.x, a1.y);
            A[ks].u[3] = pack_bf16(a1.z, a1.w);
        }
        f32x4 acc[4] = {{0.f, 0.f, 0.f, 0.f}, {0.f, 0.f, 0.f, 0.f},
                        {0.f, 0.f, 0.f, 0.f}, {0.f, 0.f, 0.f, 0.f}};
#pragma unroll
        for (int ks = 0; ks < 4; ++ks)
#pragma unroll
            for (int c = 0; c < 4; ++c)
                acc[c] = __builtin_amdgcn_mfma_f32_16x16x32_bf16(A[ks].v, B[c][ks].v, acc[c], 0, 0, 0);

        int rowD = rt * 16 + quad * 4;          // + reg
#pragma unroll
        for (int c = 0; c < 4; ++c)
#pragma unroll
            for (int r = 0; r < 4; ++r) {
                float v = acc[c][r];
                float nxt = __shfl_down(v, 1);
                int row = rowD + r;
                if (((lane & 1) == 0) && row < N)
                    h1b[(size_t)row * 32 + ((c * 16 + col) >> 1)] = pack_bf16(v, nxt);
            }
    }
}

// ---------------- GEMM2 (MFMA): act bf16 [N,64] @ W2[64,40] f32 -> h2 bf16 [N,40] ----------------
// A-fragment IS the packed actb layout: one uint4 per lane per k-step. 3 col-tiles (pad 48).

__global__ __launch_bounds__(256) void gemm2_mfma_kernel(const unsigned* __restrict__ actb,
                                                         const float* __restrict__ W2,
                                                         unsigned* __restrict__ h2b, int N) {
    int lane = threadIdx.x & 63;
    int quad = lane >> 4;
    int col  = lane & 15;

    Frag B[3][2];
#pragma unroll
    for (int c = 0; c < 3; ++c)
#pragma unroll
        for (int ks = 0; ks < 2; ++ks) {
            int n = c * 16 + col;
#pragma unroll
            for (int jj = 0; jj < 4; ++jj) {
                int k = ks * 32 + quad * 8 + 2 * jj;
                float w0 = (n < N_CLS) ? W2[k * N_CLS + n] : 0.f;
                float w1 = (n < N_CLS) ? W2[(k + 1) * N_CLS + n] : 0.f;
                B[c][ks].u[jj] = pack_bf16(w0, w1);
            }
        }

    int wave_id = blockIdx.x * 4 + (threadIdx.x >> 6);
    int nwaves  = gridDim.x * 4;
    int ntiles  = (N + 15) >> 4;

    for (int rt = wave_id; rt < ntiles; rt += nwaves) {
        int rowA = rt * 16 + col;
        Frag A[2];
#pragma unroll
        for (int ks = 0; ks < 2; ++ks) {
            uint4 u = make_uint4(0u, 0u, 0u, 0u);
            if (rowA < N)
                u = *(const uint4*)(actb + (size_t)rowA * 32 + ks * 16 + quad * 4);
            A[ks].u[0] = u.x; A[ks].u[1] = u.y; A[ks].u[2] = u.z; A[ks].u[3] = u.w;
        }
        f32x4 acc[3] = {{0.f, 0.f, 0.f, 0.f}, {0.f, 0.f, 0.f, 0.f}, {0.f, 0.f, 0.f, 0.f}};
#pragma unroll
        for (int ks = 0; ks < 2; ++ks)
#pragma unroll
            for (int c = 0; c < 3; ++c)
                acc[c] = __builtin_amdgcn_mfma_f32_16x16x32_bf16(A[ks].v, B[c][ks].v, acc[c], 0, 0, 0);

        int rowD = rt * 16 + quad * 4;
#pragma unroll
        for (int c = 0; c < 3; ++c)
#pragma unroll
            for (int r = 0; r < 4; ++r) {
                float v = acc[c][r];
                float nxt = __shfl_down(v, 1);
                int row = rowD + r;
                int pair = (c * 16 + col) >> 1;
                if (((lane & 1) == 0) && pair < 20 && row < N)
                    h2b[(size_t)row * 20 + pair] = pack_bf16(v, nxt);
            }
    }
}

// ---------------- layer-1 agg: CSR gather (bf16) + self + bias + ReLU -> act bf16 ----------------

__global__ __launch_bounds__(256) void agg1_kernel(const unsigned* __restrict__ h1b,
                                                   const int* __restrict__ csr_src,
                                                   const unsigned* __restrict__ rowptr,
                                                   const unsigned* __restrict__ deg,
                                                   const float* __restrict__ dinv,
                                                   const float* __restrict__ b1,
                                                   unsigned* __restrict__ actb, int N) {
    int wave = threadIdx.x >> 6, lane = threadIdx.x & 63;
    int sub = lane >> 5, j = lane & 31;
    int d = blockIdx.x * 4 + wave;
    if (d >= N) return;
    float dv = dinv[d];
    float acc0 = 0.f, acc1 = 0.f;
    if (sub == 0) {
        float2 v = unpack_bf16(h1b[(size_t)d * 32 + j]);
        acc0 = dv * v.x; acc1 = dv * v.y;
    }
    unsigned beg = rowptr[d];
    int len = (int)deg[d];
    int i = 0;
    for (; i + 4 <= len; i += 4) {
        int sA = csr_src[beg + i + sub];
        int sB = csr_src[beg + i + 2 + sub];
        float wA = dinv[sA], wB = dinv[sB];
        unsigned vA = h1b[(size_t)sA * 32 + j];
        unsigned vB = h1b[(size_t)sB * 32 + j];
        float2 a = unpack_bf16(vA), b = unpack_bf16(vB);
        acc0 += wA * a.x + wB * b.x;
        acc1 += wA * a.y + wB * b.y;
    }
    for (; i < len; i += 2) {
        int e = i + sub;
        if (e < len) {
            int s = csr_src[beg + e];
            float w = dinv[s];
            float2 a = unpack_bf16(h1b[(size_t)s * 32 + j]);
            acc0 += w * a.x;
            acc1 += w * a.y;
        }
    }
    acc0 += __shfl_xor(acc0, 32);
    acc1 += __shfl_xor(acc1, 32);
    if (sub == 0) {
        float2 bb = ((const float2*)b1)[j];
        float r0 = fmaxf(acc0 * dv + bb.x, 0.f);
        float r1 = fmaxf(acc1 * dv + bb.y, 0.f);
        actb[(size_t)d * 32 + j] = pack_bf16(r0, r1);
    }
}

// ---------------- layer-2 agg (bf16 gather) + bias + log_softmax -> out f32 ----------------

__global__ __launch_bounds__(256) void agg2_lsm_kernel(const unsigned* __restrict__ h2b,
                                                       const int* __restrict__ csr_src,
                                                       const unsigned* __restrict__ rowptr,
                                                       const unsigned* __restrict__ deg,
                                                       const float* __restrict__ dinv,
                                                       const float* __restrict__ b2,
                                                       float* __restrict__ out, int N) {
    int wave = threadIdx.x >> 6, lane = threadIdx.x & 63;
    int sub = lane >> 5, j = lane & 31;
    bool act = (j < 20);
    int d = blockIdx.x * 4 + wave;
    if (d >= N) return;
    float dv = dinv[d];
    float acc0 = 0.f, acc1 = 0.f;
    if (sub == 0 && act) {
        float2 v = unpack_bf16(h2b[(size_t)d * 20 + j]);
        acc0 = dv * v.x; acc1 = dv * v.y;
    }
    unsigned beg = rowptr[d];
    int len = (int)deg[d];
    int i = 0;
    for (; i + 4 <= len; i += 4) {
        int sA = csr_src[beg + i + sub];
        int sB = csr_src[beg + i + 2 + sub];
        float wA = dinv[sA], wB = dinv[sB];
        if (act) {
            float2 a = unpack_bf16(h2b[(size_t)sA * 20 + j]);
            float2 b = unpack_bf16(h2b[(size_t)sB * 20 + j]);
            acc0 += wA * a.x + wB * b.x;
            acc1 += wA * a.y + wB * b.y;
        }
    }
    for (; i < len; i += 2) {
        int e = i + sub;
        if (e < len && act) {
            int s = csr_src[beg + e];
            float w = dinv[s];
            float2 a = unpack_bf16(h2b[(size_t)s * 20 + j]);
            acc0 += w * a.x;
            acc1 += w * a.y;
        }
    }
    acc0 += __shfl_xor(acc0, 32);
    acc1 += __shfl_xor(acc1, 32);
    float v0 = -1e30f, v1 = -1e30f;
    if (act) {
        float2 bb = ((const float2*)b2)[j];
        v0 = acc0 * dv + bb.x;
        v1 = acc1 * dv + bb.y;
    }
    float m = fmaxf(v0, v1);
#pragma unroll
    for (int off = 32; off > 0; off >>= 1)
        m = fmaxf(m, __shfl_xor(m, off));
    float ex = (act && sub == 0) ? (expf(v0 - m) + expf(v1 - m)) : 0.f;
#pragma unroll
    for (int off = 32; off > 0; off >>= 1)
        ex += __shfl_xor(ex, off);
    float ls = logf(ex);
    if (act && sub == 0) {
        float2* orow = (float2*)(out + (size_t)d * N_CLS);
        orow[j] = make_float2(v0 - m - ls, v1 - m - ls);
    }
}

// ---------------- launch ----------------

static inline size_t align_up(size_t x) { return (x + 255) & ~(size_t)255; }

extern "C" void kernel_launch(void* const* d_in, const int* in_sizes, int n_in,
                              void* d_out, int out_size, void* d_ws, size_t ws_size,
                              hipStream_t stream) {
    const float* x  = (const float*)d_in[0];
    const int*   ei = (const int*)d_in[1];
    const float* W1 = (const float*)d_in[2];
    const float* b1 = (const float*)d_in[3];
    const float* W2 = (const float*)d_in[4];
    const float* b2 = (const float*)d_in[5];

    int N = in_sizes[0] / N_FEAT;     // 100000
    int E = in_sizes[1] / 2;          // 1600000
    int nb = (N + SCAN_B - 1) / SCAN_B;

    char* ws = (char*)d_ws;
    int*      flag    = (int*)ws;       ws += 256;
    unsigned* deg     = (unsigned*)ws;  ws += align_up((size_t)N * 4);
    float*    dinv    = (float*)ws;     ws += align_up((size_t)N * 4);
    unsigned* rowptr  = (unsigned*)ws;  ws += align_up((size_t)N * 4);
    unsigned* cursor  = (unsigned*)ws;  ws += align_up((size_t)N * 4);
    unsigned* bsums   = (unsigned*)ws;  ws += align_up((size_t)nb * 4);
    int*      csr_src = (int*)ws;       ws += align_up((size_t)E * 4);
    unsigned* h1b     = (unsigned*)ws;  ws += align_up((size_t)N * 32 * 4);   // bf16 [N,64]
    unsigned* actb    = (unsigned*)ws;  ws += align_up((size_t)N * 32 * 4);   // bf16 [N,64]
    unsigned* h2b     = (unsigned*)ws;  ws += align_up((size_t)N * 20 * 4);   // bf16 [N,40]

    hipMemsetAsync(deg, 0, (size_t)N * 4, stream);

    detect_layout_kernel<<<1, 64, 0, stream>>>(ei, flag);
    count_kernel<<<FILL_BLOCKS, 256, 0, stream>>>(ei, flag, deg, E, N);
    dinv_kernel<<<(N + 255) / 256, 256, 0, stream>>>(deg, dinv, N);

    scan1_kernel<<<nb, SCAN_B, 0, stream>>>(deg, rowptr, bsums, N);
    scan2_kernel<<<1, 512, 0, stream>>>(bsums, nb);
    scan3_kernel<<<nb, SCAN_B, 0, stream>>>(rowptr, bsums, cursor, N);
    csr_fill_kernel<<<FILL_BLOCKS, 256, 0, stream>>>(ei, flag, cursor, csr_src, E, N);

    // layer 1
    gemm1_mfma_kernel<<<512, 256, 0, stream>>>(x, W1, h1b, N);
    agg1_kernel<<<(N + 3) / 4, 256, 0, stream>>>(h1b, csr_src, rowptr, deg, dinv, b1, actb, N);

    // layer 2
    gemm2_mfma_kernel<<<512, 256, 0, stream>>>(actb, W2, h2b, N);
    agg2_lsm_kernel<<<(N + 3) / 4, 256, 0, stream>>>(h2b, csr_src, rowptr, deg, dinv, b2, (float*)d_out, N);
}

// Round 7
// 377.635 us; speedup vs baseline: 2.5819x; 1.0642x over previous
//
#include <hip/hip_runtime.h>
#include <hip/hip_bf16.h>
#include <string.h>

#define N_FEAT 128
#define HIDDEN 64
#define N_CLS  40
#define SCAN_B 256
#define FILL_BLOCKS 1024   // 8 range-groups x 128 blocks

typedef __bf16 bf16x8 __attribute__((ext_vector_type(8)));
typedef float  f32x4  __attribute__((ext_vector_type(4)));

union Frag { unsigned u[4]; bf16x8 v; };

// ---------------- bf16 pack/unpack (manual, RNE) ----------------

static __device__ inline unsigned pack_bf16(float a, float b) {
    unsigned ba = __float_as_uint(a);
    unsigned bb = __float_as_uint(b);
    unsigned ra = (ba + 0x7fffu + ((ba >> 16) & 1u)) >> 16;
    unsigned rb = (bb + 0x7fffu + ((bb >> 16) & 1u)) >> 16;
    return (ra & 0xffffu) | (rb << 16);
}

static __device__ inline float2 unpack_bf16(unsigned v) {
    return make_float2(__uint_as_float(v << 16), __uint_as_float(v & 0xffff0000u));
}

// ---------------- edge layout detection ----------------

__global__ void detect_layout_kernel(const int* __restrict__ ei, int* __restrict__ flag) {
    int lane = threadIdx.x;                 // one wave
    int v = ei[2 * lane + 1];
    unsigned long long b = __ballot(v != 0);
    if (lane == 0) flag[0] = (b == 0ull) ? 1 : 0;   // 1 => int64 layout
}

// ---------------- degree count, XCD-range partitioned ----------------

__global__ __launch_bounds__(256) void count_kernel(const int* __restrict__ ei,
                                                    const int* __restrict__ flag,
                                                    unsigned* __restrict__ deg, int E, int N) {
    int r  = blockIdx.x & 7;
    int gb = blockIdx.x >> 3;
    int nb = gridDim.x >> 3;
    int rng = (N + 7) >> 3;
    int lo = r * rng;
    int hi = min(N, lo + rng);
    bool is64 = (flag[0] != 0);
    const int* dstp = is64 ? (ei + 2 * E) : (ei + E);
    int stride = is64 ? 2 : 1;
    for (int e = gb * 256 + threadIdx.x; e < E; e += nb * 256) {
        int d = dstp[(size_t)e * stride];
        if (d >= lo && d < hi) atomicAdd(&deg[d], 1u);
    }
}

// ---------------- exclusive scan of deg -> rowptr (+ fused dinv) ----------------

__global__ void scan1_kernel(const unsigned* __restrict__ deg, unsigned* __restrict__ rowptr,
                             unsigned* __restrict__ blockSums, float* __restrict__ dinv, int N) {
    __shared__ unsigned tmp[SCAN_B];
    int i = blockIdx.x * SCAN_B + threadIdx.x;
    unsigned v = (i < N) ? deg[i] : 0u;
    if (i < N) dinv[i] = rsqrtf((float)(v + 1u));   // +1 self-loop
    tmp[threadIdx.x] = v;
    __syncthreads();
#pragma unroll
    for (int off = 1; off < SCAN_B; off <<= 1) {
        unsigned t = (threadIdx.x >= off) ? tmp[threadIdx.x - off] : 0u;
        __syncthreads();
        tmp[threadIdx.x] += t;
        __syncthreads();
    }
    if (i < N) rowptr[i] = tmp[threadIdx.x] - v;
    if (threadIdx.x == SCAN_B - 1) blockSums[blockIdx.x] = tmp[threadIdx.x];
}

__global__ void scan2_kernel(unsigned* __restrict__ blockSums, int nb) {
    __shared__ unsigned tmp[512];
    unsigned v = (threadIdx.x < (unsigned)nb) ? blockSums[threadIdx.x] : 0u;
    tmp[threadIdx.x] = v;
    __syncthreads();
#pragma unroll
    for (int off = 1; off < 512; off <<= 1) {
        unsigned t = (threadIdx.x >= (unsigned)off) ? tmp[threadIdx.x - off] : 0u;
        __syncthreads();
        tmp[threadIdx.x] += t;
        __syncthreads();
    }
    if (threadIdx.x < (unsigned)nb) blockSums[threadIdx.x] = tmp[threadIdx.x] - v;
}

__global__ void scan3_kernel(unsigned* __restrict__ rowptr, const unsigned* __restrict__ blockSums,
                             unsigned* __restrict__ cursor, int N) {
    int i = blockIdx.x * SCAN_B + threadIdx.x;
    if (i < N) {
        unsigned v = rowptr[i] + blockSums[blockIdx.x];
        rowptr[i] = v;
        cursor[i] = v;
    }
}

// ---------------- CSR fill, XCD-range partitioned ----------------

__global__ __launch_bounds__(256) void csr_fill_kernel(const int* __restrict__ ei,
                                                       const int* __restrict__ flag,
                                                       unsigned* __restrict__ cursor,
                                                       int* __restrict__ csr_src, int E, int N) {
    int r  = blockIdx.x & 7;
    int gb = blockIdx.x >> 3;
    int nb = gridDim.x >> 3;
    int rng = (N + 7) >> 3;
    int lo = r * rng;
    int hi = min(N, lo + rng);
    bool is64 = (flag[0] != 0);
    const int* dstp = is64 ? (ei + 2 * E) : (ei + E);
    int stride = is64 ? 2 : 1;
    for (int e = gb * 256 + threadIdx.x; e < E; e += nb * 256) {
        int d = dstp[(size_t)e * stride];
        if (d >= lo && d < hi) {
            int s = ei[(size_t)e * stride];
            unsigned slot = atomicAdd(&cursor[d], 1u);
            csr_src[slot] = s;
        }
    }
}

// ---------------- GEMM1 (MFMA): x[N,128] f32 @ W1[128,64] f32 -> h1 bf16 [N,64] ----------------

__global__ __launch_bounds__(256) void gemm1_mfma_kernel(const float* __restrict__ x,
                                                         const float* __restrict__ W1,
                                                         unsigned* __restrict__ h1b, int N) {
    int lane = threadIdx.x & 63;
    int quad = lane >> 4;
    int col  = lane & 15;

    Frag B[4][4];
#pragma unroll
    for (int c = 0; c < 4; ++c)
#pragma unroll
        for (int ks = 0; ks < 4; ++ks) {
            int n = c * 16 + col;
#pragma unroll
            for (int jj = 0; jj < 4; ++jj) {
                int k = ks * 32 + quad * 8 + 2 * jj;
                B[c][ks].u[jj] = pack_bf16(W1[k * HIDDEN + n], W1[(k + 1) * HIDDEN + n]);
            }
        }

    int wave_id = blockIdx.x * 4 + (threadIdx.x >> 6);
    int nwaves  = gridDim.x * 4;
    int ntiles  = (N + 15) >> 4;

    for (int rt = wave_id; rt < ntiles; rt += nwaves) {
        int rowA = rt * 16 + col;
        Frag A[4];
#pragma unroll
        for (int ks = 0; ks < 4; ++ks) {
            float4 a0 = make_float4(0.f, 0.f, 0.f, 0.f), a1 = a0;
            if (rowA < N) {
                const float4* ap = (const float4*)(x + (size_t)rowA * N_FEAT + ks * 32 + quad * 8);
                a0 = ap[0];
                a1 = ap[1];
            }
            A[ks].u[0] = pack_bf16(a0.x, a0.y);
            A[ks].u[1] = pack_bf16(a0.z, a0.w);
            A[ks].u[2] = pack_bf16(a1.x, a1.y);
            A[ks].u[3] = pack_bf16(a1.z, a1.w);
        }
        f32x4 acc[4] = {{0.f, 0.f, 0.f, 0.f}, {0.f, 0.f, 0.f, 0.f},
                        {0.f, 0.f, 0.f, 0.f}, {0.f, 0.f, 0.f, 0.f}};
#pragma unroll
        for (int ks = 0; ks < 4; ++ks)
#pragma unroll
            for (int c = 0; c < 4; ++c)
                acc[c] = __builtin_amdgcn_mfma_f32_16x16x32_bf16(A[ks].v, B[c][ks].v, acc[c], 0, 0, 0);

        int rowD = rt * 16 + quad * 4;
#pragma unroll
        for (int c = 0; c < 4; ++c)
#pragma unroll
            for (int r = 0; r < 4; ++r) {
                float v = acc[c][r];
                float nxt = __shfl_down(v, 1);
                int row = rowD + r;
                if (((lane & 1) == 0) && row < N)
                    h1b[(size_t)row * 32 + ((c * 16 + col) >> 1)] = pack_bf16(v, nxt);
            }
    }
}

// ---------------- GEMM2 (MFMA): act bf16 [N,64] @ W2[64,40] f32 -> h2 bf16 [N,40] ----------------

__global__ __launch_bounds__(256) void gemm2_mfma_kernel(const unsigned* __restrict__ actb,
                                                         const float* __restrict__ W2,
                                                         unsigned* __restrict__ h2b, int N) {
    int lane = threadIdx.x & 63;
    int quad = lane >> 4;
    int col  = lane & 15;

    Frag B[3][2];
#pragma unroll
    for (int c = 0; c < 3; ++c)
#pragma unroll
        for (int ks = 0; ks < 2; ++ks) {
            int n = c * 16 + col;
#pragma unroll
            for (int jj = 0; jj < 4; ++jj) {
                int k = ks * 32 + quad * 8 + 2 * jj;
                float w0 = (n < N_CLS) ? W2[k * N_CLS + n] : 0.f;
                float w1 = (n < N_CLS) ? W2[(k + 1) * N_CLS + n] : 0.f;
                B[c][ks].u[jj] = pack_bf16(w0, w1);
            }
        }

    int wave_id = blockIdx.x * 4 + (threadIdx.x >> 6);
    int nwaves  = gridDim.x * 4;
    int ntiles  = (N + 15) >> 4;

    for (int rt = wave_id; rt < ntiles; rt += nwaves) {
        int rowA = rt * 16 + col;
        Frag A[2];
#pragma unroll
        for (int ks = 0; ks < 2; ++ks) {
            uint4 u = make_uint4(0u, 0u, 0u, 0u);
            if (rowA < N)
                u = *(const uint4*)(actb + (size_t)rowA * 32 + ks * 16 + quad * 4);
            A[ks].u[0] = u.x; A[ks].u[1] = u.y; A[ks].u[2] = u.z; A[ks].u[3] = u.w;
        }
        f32x4 acc[3] = {{0.f, 0.f, 0.f, 0.f}, {0.f, 0.f, 0.f, 0.f}, {0.f, 0.f, 0.f, 0.f}};
#pragma unroll
        for (int ks = 0; ks < 2; ++ks)
#pragma unroll
            for (int c = 0; c < 3; ++c)
                acc[c] = __builtin_amdgcn_mfma_f32_16x16x32_bf16(A[ks].v, B[c][ks].v, acc[c], 0, 0, 0);

        int rowD = rt * 16 + quad * 4;
#pragma unroll
        for (int c = 0; c < 3; ++c)
#pragma unroll
            for (int r = 0; r < 4; ++r) {
                float v = acc[c][r];
                float nxt = __shfl_down(v, 1);
                int row = rowD + r;
                int pair = (c * 16 + col) >> 1;
                if (((lane & 1) == 0) && pair < 20 && row < N)
                    h2b[(size_t)row * 20 + pair] = pack_bf16(v, nxt);
            }
    }
}

// ---------------- layer-1 agg: 8-edge unrolled CSR gather + self + bias + ReLU ----------------

__global__ __launch_bounds__(256) void agg1_kernel(const unsigned* __restrict__ h1b,
                                                   const int* __restrict__ csr_src,
                                                   const unsigned* __restrict__ rowptr,
                                                   const unsigned* __restrict__ deg,
                                                   const float* __restrict__ dinv,
                                                   const float* __restrict__ b1,
                                                   unsigned* __restrict__ actb, int N) {
    int wave = threadIdx.x >> 6, lane = threadIdx.x & 63;
    int sub = lane >> 5, j = lane & 31;
    int d = blockIdx.x * 4 + wave;
    if (d >= N) return;
    float dv = dinv[d];
    float acc0 = 0.f, acc1 = 0.f;
    if (sub == 0) {
        float2 v = unpack_bf16(h1b[(size_t)d * 32 + j]);
        acc0 = dv * v.x; acc1 = dv * v.y;
    }
    unsigned beg = rowptr[d];
    int len = (int)deg[d];
    int i = 0;
    // 8 edges per iteration: 4 independent gather chains per half-wave
    for (; i + 8 <= len; i += 8) {
        int s0 = csr_src[beg + i + sub];
        int s1 = csr_src[beg + i + 2 + sub];
        int s2 = csr_src[beg + i + 4 + sub];
        int s3 = csr_src[beg + i + 6 + sub];
        float w0 = dinv[s0], w1 = dinv[s1], w2 = dinv[s2], w3 = dinv[s3];
        unsigned v0 = h1b[(size_t)s0 * 32 + j];
        unsigned v1 = h1b[(size_t)s1 * 32 + j];
        unsigned v2 = h1b[(size_t)s2 * 32 + j];
        unsigned v3 = h1b[(size_t)s3 * 32 + j];
        float2 a0 = unpack_bf16(v0), a1 = unpack_bf16(v1);
        float2 a2 = unpack_bf16(v2), a3 = unpack_bf16(v3);
        acc0 += w0 * a0.x + w1 * a1.x + w2 * a2.x + w3 * a3.x;
        acc1 += w0 * a0.y + w1 * a1.y + w2 * a2.y + w3 * a3.y;
    }
    for (; i + 4 <= len; i += 4) {
        int sA = csr_src[beg + i + sub];
        int sB = csr_src[beg + i + 2 + sub];
        float wA = dinv[sA], wB = dinv[sB];
        float2 a = unpack_bf16(h1b[(size_t)sA * 32 + j]);
        float2 b = unpack_bf16(h1b[(size_t)sB * 32 + j]);
        acc0 += wA * a.x + wB * b.x;
        acc1 += wA * a.y + wB * b.y;
    }
    for (; i < len; i += 2) {
        int e = i + sub;
        if (e < len) {
            int s = csr_src[beg + e];
            float w = dinv[s];
            float2 a = unpack_bf16(h1b[(size_t)s * 32 + j]);
            acc0 += w * a.x;
            acc1 += w * a.y;
        }
    }
    acc0 += __shfl_xor(acc0, 32);
    acc1 += __shfl_xor(acc1, 32);
    if (sub == 0) {
        float2 bb = ((const float2*)b1)[j];
        float r0 = fmaxf(acc0 * dv + bb.x, 0.f);
        float r1 = fmaxf(acc1 * dv + bb.y, 0.f);
        actb[(size_t)d * 32 + j] = pack_bf16(r0, r1);
    }
}

// ---------------- layer-2 agg: 8-edge unrolled gather + bias + log_softmax ----------------

__global__ __launch_bounds__(256) void agg2_lsm_kernel(const unsigned* __restrict__ h2b,
                                                       const int* __restrict__ csr_src,
                                                       const unsigned* __restrict__ rowptr,
                                                       const unsigned* __restrict__ deg,
                                                       const float* __restrict__ dinv,
                                                       const float* __restrict__ b2,
                                                       float* __restrict__ out, int N) {
    int wave = threadIdx.x >> 6, lane = threadIdx.x & 63;
    int sub = lane >> 5, j = lane & 31;
    bool act = (j < 20);
    int d = blockIdx.x * 4 + wave;
    if (d >= N) return;
    float dv = dinv[d];
    float acc0 = 0.f, acc1 = 0.f;
    if (sub == 0 && act) {
        float2 v = unpack_bf16(h2b[(size_t)d * 20 + j]);
        acc0 = dv * v.x; acc1 = dv * v.y;
    }
    unsigned beg = rowptr[d];
    int len = (int)deg[d];
    int i = 0;
    for (; i + 8 <= len; i += 8) {
        int s0 = csr_src[beg + i + sub];
        int s1 = csr_src[beg + i + 2 + sub];
        int s2 = csr_src[beg + i + 4 + sub];
        int s3 = csr_src[beg + i + 6 + sub];
        float w0 = dinv[s0], w1 = dinv[s1], w2 = dinv[s2], w3 = dinv[s3];
        if (act) {
            float2 a0 = unpack_bf16(h2b[(size_t)s0 * 20 + j]);
            float2 a1 = unpack_bf16(h2b[(size_t)s1 * 20 + j]);
            float2 a2 = unpack_bf16(h2b[(size_t)s2 * 20 + j]);
            float2 a3 = unpack_bf16(h2b[(size_t)s3 * 20 + j]);
            acc0 += w0 * a0.x + w1 * a1.x + w2 * a2.x + w3 * a3.x;
            acc1 += w0 * a0.y + w1 * a1.y + w2 * a2.y + w3 * a3.y;
        }
    }
    for (; i + 4 <= len; i += 4) {
        int sA = csr_src[beg + i + sub];
        int sB = csr_src[beg + i + 2 + sub];
        float wA = dinv[sA], wB = dinv[sB];
        if (act) {
            float2 a = unpack_bf16(h2b[(size_t)sA * 20 + j]);
            float2 b = unpack_bf16(h2b[(size_t)sB * 20 + j]);
            acc0 += wA * a.x + wB * b.x;
            acc1 += wA * a.y + wB * b.y;
        }
    }
    for (; i < len; i += 2) {
        int e = i + sub;
        if (e < len && act) {
            int s = csr_src[beg + e];
            float w = dinv[s];
            float2 a = unpack_bf16(h2b[(size_t)s * 20 + j]);
            acc0 += w * a.x;
            acc1 += w * a.y;
        }
    }
    acc0 += __shfl_xor(acc0, 32);
    acc1 += __shfl_xor(acc1, 32);
    float v0 = -1e30f, v1 = -1e30f;
    if (act) {
        float2 bb = ((const float2*)b2)[j];
        v0 = acc0 * dv + bb.x;
        v1 = acc1 * dv + bb.y;
    }
    float m = fmaxf(v0, v1);
#pragma unroll
    for (int off = 32; off > 0; off >>= 1)
        m = fmaxf(m, __shfl_xor(m, off));
    float ex = (act && sub == 0) ? (expf(v0 - m) + expf(v1 - m)) : 0.f;
#pragma unroll
    for (int off = 32; off > 0; off >>= 1)
        ex += __shfl_xor(ex, off);
    float ls = logf(ex);
    if (act && sub == 0) {
        float2* orow = (float2*)(out + (size_t)d * N_CLS);
        orow[j] = make_float2(v0 - m - ls, v1 - m - ls);
    }
}

// ---------------- launch ----------------

static inline size_t align_up(size_t x) { return (x + 255) & ~(size_t)255; }

extern "C" void kernel_launch(void* const* d_in, const int* in_sizes, int n_in,
                              void* d_out, int out_size, void* d_ws, size_t ws_size,
                              hipStream_t stream) {
    const float* x  = (const float*)d_in[0];
    const int*   ei = (const int*)d_in[1];
    const float* W1 = (const float*)d_in[2];
    const float* b1 = (const float*)d_in[3];
    const float* W2 = (const float*)d_in[4];
    const float* b2 = (const float*)d_in[5];

    int N = in_sizes[0] / N_FEAT;     // 100000
    int E = in_sizes[1] / 2;          // 1600000
    int nb = (N + SCAN_B - 1) / SCAN_B;

    char* ws = (char*)d_ws;
    int*      flag    = (int*)ws;       ws += 256;
    unsigned* deg     = (unsigned*)ws;  ws += align_up((size_t)N * 4);
    float*    dinv    = (float*)ws;     ws += align_up((size_t)N * 4);
    unsigned* rowptr  = (unsigned*)ws;  ws += align_up((size_t)N * 4);
    unsigned* cursor  = (unsigned*)ws;  ws += align_up((size_t)N * 4);
    unsigned* bsums   = (unsigned*)ws;  ws += align_up((size_t)nb * 4);
    int*      csr_src = (int*)ws;       ws += align_up((size_t)E * 4);
    unsigned* h1b     = (unsigned*)ws;  ws += align_up((size_t)N * 32 * 4);   // bf16 [N,64]
    unsigned* actb    = (unsigned*)ws;  ws += align_up((size_t)N * 32 * 4);   // bf16 [N,64]
    unsigned* h2b     = (unsigned*)ws;  ws += align_up((size_t)N * 20 * 4);   // bf16 [N,40]

    hipMemsetAsync(deg, 0, (size_t)N * 4, stream);

    detect_layout_kernel<<<1, 64, 0, stream>>>(ei, flag);
    count_kernel<<<FILL_BLOCKS, 256, 0, stream>>>(ei, flag, deg, E, N);

    scan1_kernel<<<nb, SCAN_B, 0, stream>>>(deg, rowptr, bsums, dinv, N);
    scan2_kernel<<<1, 512, 0, stream>>>(bsums, nb);
    scan3_kernel<<<nb, SCAN_B, 0, stream>>>(rowptr, bsums, cursor, N);
    csr_fill_kernel<<<FILL_BLOCKS, 256, 0, stream>>>(ei, flag, cursor, csr_src, E, N);

    // layer 1
    gemm1_mfma_kernel<<<512, 256, 0, stream>>>(x, W1, h1b, N);
    agg1_kernel<<<(N + 3) / 4, 256, 0, stream>>>(h1b, csr_src, rowptr, deg, dinv, b1, actb, N);

    // layer 2
    gemm2_mfma_kernel<<<512, 256, 0, stream>>>(actb, W2, h2b, N);
    agg2_lsm_kernel<<<(N + 3) / 4, 256, 0, stream>>>(h2b, csr_src, rowptr, deg, dinv, b2, (float*)d_out, N);
}